// Round 1
// baseline (493.053 us; speedup 1.0000x reference)
//
#include <hip/hip_runtime.h>
#include <math.h>

#define BB 4
#define NT 1024
#define NSP 256
#define C 128
#define HEADS 8
#define HID 340
#define HID2 680
#define EPS 1e-5f

// workspace float offsets
#define WS_Q    0
#define WS_K    524288
#define WS_VT   1048576
#define WS_AO   1572864
#define WS_X1   2097152
#define WS_XN2  2621440
#define WS_PIN  3145728
#define WS_GLU  5931008
#define WS_MISC 7323648

// ---------------- K0: precompute piecewise-linear bias-MLP coefficients ----------------
__global__ void k0_prep(const float* __restrict__ bw1, const float* __restrict__ bb1,
                        const float* __restrict__ bw2, float* __restrict__ misc) {
    int t = threadIdx.x;
    if (t < HEADS) {
        float P = 0.f, Nn = 0.f;
        for (int k = 0; k < 16; ++k) {
            float w1 = bw1[k];
            float w2 = bw2[t * 16 + k];
            if (w1 > 0.f) P += w2 * w1; else Nn += w2 * w1;
        }
        misc[t] = P;
        misc[8 + t] = Nn;
    }
    if (t == 0) {
        int f = 1;
        for (int k = 0; k < 16; ++k) if (bb1[k] != 0.f) f = 0;
        misc[16] = (float)f;
    }
}

// ---------------- K1: LN1 + QKV projection (8 tokens / block) ----------------
__global__ __launch_bounds__(256) void k1_ln_qkv(
    const float* __restrict__ x, const float* __restrict__ s1, const float* __restrict__ b1,
    const float* __restrict__ qkv_w, const float* __restrict__ qkv_b, float* __restrict__ ws) {
    __shared__ float sxn[8][C];
    __shared__ float part[4][2];
    int tid = threadIdx.x;
    int g = tid >> 7, c = tid & 127;
    int wv = tid >> 6, lane = tid & 63;
    int tb = blockIdx.x * 8;

    for (int pass = 0; pass < 4; ++pass) {
        int tok = pass * 2 + g;
        float v = x[(size_t)(tb + tok) * C + c];
        float s = v, sq = v * v;
        #pragma unroll
        for (int off = 32; off; off >>= 1) { s += __shfl_xor(s, off); sq += __shfl_xor(sq, off); }
        if (lane == 0) { part[wv][0] = s; part[wv][1] = sq; }
        __syncthreads();
        float tot = part[g * 2][0] + part[g * 2 + 1][0];
        float tot2 = part[g * 2][1] + part[g * 2 + 1][1];
        float m = tot * (1.0f / C);
        float var = tot2 * (1.0f / C) - m * m;
        float inv = rsqrtf(var + EPS);
        sxn[tok][c] = (v - m) * inv * s1[c] + b1[c];
        __syncthreads();
    }

    float* qw = ws + WS_Q;
    float* kw = ws + WS_K;
    float* vtw = ws + WS_VT;
    for (int oo = tid; oo < 384; oo += 256) {
        const float4* wr = (const float4*)(qkv_w + (size_t)oo * C);
        float bbv = qkv_b[oo];
        float acc[8];
        #pragma unroll
        for (int t = 0; t < 8; ++t) acc[t] = bbv;
        #pragma unroll 4
        for (int ic4 = 0; ic4 < 32; ++ic4) {
            float4 w4 = wr[ic4];
            #pragma unroll
            for (int t = 0; t < 8; ++t) {
                acc[t] += w4.x * sxn[t][ic4 * 4 + 0] + w4.y * sxn[t][ic4 * 4 + 1]
                        + w4.z * sxn[t][ic4 * 4 + 2] + w4.w * sxn[t][ic4 * 4 + 3];
            }
        }
        int m3 = oo >> 7, h = (oo >> 4) & 7, dd = oo & 15;
        for (int t = 0; t < 8; ++t) {
            int tok = tb + t;
            int b = tok >> 10, i = tok & 1023;
            if (m3 == 0)      qw[(size_t)tok * C + h * 16 + dd] = acc[t] * 0.25f; // fold d^-0.5
            else if (m3 == 1) kw[(((size_t)b * 8 + h) * NT + i) * 16 + dd] = acc[t];
            else              vtw[(((size_t)b * 8 + h) * 16 + dd) * NT + i] = acc[t];
        }
    }
}

// ---------------- K2: fused logits + bias-MLP + softmax + attn-write + PV ----------------
__global__ __launch_bounds__(256, 1) void k2_attn(
    const float* __restrict__ bias, const float* __restrict__ bb2v,
    const float* __restrict__ bw1v, const float* __restrict__ bb1v, const float* __restrict__ bw2v,
    float* __restrict__ ws, float* __restrict__ attn_out) {
    __shared__ float lg[4][HEADS][NT];   // 128 KB logits->probs
    __shared__ float sbias[4][NT];       // 16 KB bias rows
    __shared__ float sq[4][C];           // 2 KB q rows (pre-scaled)
    __shared__ float sPN[24];
    __shared__ float sw1[16], sb1[16], sw2[128];
    __shared__ int sfast;

    int tid = threadIdx.x;
    int blk = blockIdx.x;
    int b = blk >> 8;
    int i0 = (blk & 255) << 2;
    const float* qw = ws + WS_Q;
    const float* kw = ws + WS_K;
    const float* vtw = ws + WS_VT;
    const float* misc = ws + WS_MISC;

    for (int idx = tid; idx < 4096; idx += 256) {
        int r = idx >> 10, j = idx & 1023;
        sbias[r][j] = bias[((size_t)b * NT + i0 + r) * NT + j];
    }
    for (int idx = tid; idx < 512; idx += 256)
        sq[idx >> 7][idx & 127] = qw[((size_t)b * NT + i0 + (idx >> 7)) * C + (idx & 127)];
    if (tid < 24) sPN[tid] = (tid < 16) ? misc[tid] : bb2v[tid - 16];
    if (tid >= 32 && tid < 48) { sw1[tid - 32] = bw1v[tid - 32]; sb1[tid - 32] = bb1v[tid - 32]; }
    if (tid >= 64 && tid < 192) sw2[tid - 64] = bw2v[tid - 64];
    if (tid == 0) sfast = (misc[16] != 0.0f) ? 1 : 0;
    __syncthreads();
    bool fast = (sfast != 0);

    // Phase A: logits
    for (int h = 0; h < HEADS; ++h) {
        float qh[4][16];
        #pragma unroll
        for (int r = 0; r < 4; ++r)
            #pragma unroll
            for (int dd = 0; dd < 16; ++dd) qh[r][dd] = sq[r][h * 16 + dd];
        float Ph = sPN[h], Nh = sPN[8 + h], c2 = sPN[16 + h];
        const float* kbase = kw + ((size_t)(b * 8 + h)) * NT * 16;
        for (int jj = 0; jj < 4; ++jj) {
            int j = jj * 256 + tid;
            const float4* kr = (const float4*)(kbase + (size_t)j * 16);
            float4 k0 = kr[0], k1 = kr[1], k2 = kr[2], k3 = kr[3];
            #pragma unroll
            for (int r = 0; r < 4; ++r) {
                float dot = qh[r][0] * k0.x + qh[r][1] * k0.y + qh[r][2] * k0.z + qh[r][3] * k0.w
                          + qh[r][4] * k1.x + qh[r][5] * k1.y + qh[r][6] * k1.z + qh[r][7] * k1.w
                          + qh[r][8] * k2.x + qh[r][9] * k2.y + qh[r][10] * k2.z + qh[r][11] * k2.w
                          + qh[r][12] * k3.x + qh[r][13] * k3.y + qh[r][14] * k3.z + qh[r][15] * k3.w;
                float bv = sbias[r][j];
                float lb;
                if (fast) {
                    lb = bv * (bv > 0.f ? Ph : Nh) + c2;
                } else {
                    lb = c2;
                    #pragma unroll
                    for (int k = 0; k < 16; ++k) {
                        float t = bv * sw1[k] + sb1[k];
                        if (t > 0.f) lb += sw2[h * 16 + k] * t;
                    }
                }
                lg[r][h][j] = dot + lb;
            }
        }
    }
    __syncthreads();

    // Phase B: softmax + normalized attn write
    int wv = tid >> 6, lane = tid & 63;
    for (int p = wv; p < 32; p += 4) {
        int r = p >> 3, h = p & 7;
        float vals[16];
        float vmax = -1e30f;
        #pragma unroll
        for (int k = 0; k < 16; ++k) { vals[k] = lg[r][h][lane + 64 * k]; vmax = fmaxf(vmax, vals[k]); }
        #pragma unroll
        for (int off = 32; off; off >>= 1) vmax = fmaxf(vmax, __shfl_xor(vmax, off));
        float ssum = 0.f;
        #pragma unroll
        for (int k = 0; k < 16; ++k) { vals[k] = __expf(vals[k] - vmax); ssum += vals[k]; }
        #pragma unroll
        for (int off = 32; off; off >>= 1) ssum += __shfl_xor(ssum, off);
        float inv = 1.0f / ssum;
        float* gbase = attn_out + (((size_t)b * 8 + h) * NT + i0 + r) * NT;
        #pragma unroll
        for (int k = 0; k < 16; ++k) {
            float pv = vals[k] * inv;
            lg[r][h][lane + 64 * k] = pv;
            gbase[lane + 64 * k] = pv;
        }
    }
    __syncthreads();

    // Phase C: PV — lane = (row r, dim dd); V transposed so loads are float4
    int r = lane >> 4, dd = lane & 15;
    float* ao = ws + WS_AO;
    for (int hp = 0; hp < 2; ++hp) {
        int h = wv + hp * 4;
        const float4* vr = (const float4*)(vtw + (((size_t)b * 8 + h) * 16 + dd) * NT);
        const float4* pr = (const float4*)(&lg[r][h][0]);
        float a0 = 0.f, a1 = 0.f, a2 = 0.f, a3 = 0.f;
        #pragma unroll 4
        for (int j4 = 0; j4 < 256; ++j4) {
            float4 pv = pr[j4];
            float4 vv = vr[j4];
            a0 += pv.x * vv.x; a1 += pv.y * vv.y; a2 += pv.z * vv.z; a3 += pv.w * vv.w;
        }
        ao[((size_t)b * NT + i0 + r) * C + h * 16 + dd] = a0 + a1 + a2 + a3;
    }
}

// ---------------- K3: proj + residual1 + LN2 ----------------
__global__ __launch_bounds__(128) void k3_proj(
    const float* __restrict__ x, const float* __restrict__ proj_w, const float* __restrict__ proj_b,
    const float* __restrict__ g1, const float* __restrict__ s2, const float* __restrict__ b2,
    float* __restrict__ ws) {
    __shared__ float sao[C];
    __shared__ float part[2][2];
    int tok = blockIdx.x;
    int c = threadIdx.x;
    const float* ao = ws + WS_AO;
    sao[c] = ao[(size_t)tok * C + c];
    __syncthreads();
    float acc = proj_b[c];
    const float4* wr = (const float4*)(proj_w + (size_t)c * C);
    const float4* ar = (const float4*)sao;
    #pragma unroll 8
    for (int q = 0; q < 32; ++q) {
        float4 w4 = wr[q], a4 = ar[q];
        acc += w4.x * a4.x + w4.y * a4.y + w4.z * a4.z + w4.w * a4.w;
    }
    float x1 = x[(size_t)tok * C + c] + g1[c] * acc;
    ws[WS_X1 + (size_t)tok * C + c] = x1;
    int wv = c >> 6, lane = c & 63;
    float s = x1, sq = x1 * x1;
    #pragma unroll
    for (int off = 32; off; off >>= 1) { s += __shfl_xor(s, off); sq += __shfl_xor(sq, off); }
    if (lane == 0) { part[wv][0] = s; part[wv][1] = sq; }
    __syncthreads();
    float tot = part[0][0] + part[1][0];
    float tot2 = part[0][1] + part[1][1];
    float m = tot * (1.0f / C);
    float var = tot2 * (1.0f / C) - m * m;
    float xn2 = (x1 - m) * rsqrtf(var + EPS) * s2[c] + b2[c];
    int bt = tok >> 8, n = tok & 255;
    ws[WS_XN2 + ((size_t)bt * C + c) * NSP + n] = xn2;
}

// ---------------- K4: pin 1x1 conv (GEMM, 16 spatial / block) ----------------
__global__ __launch_bounds__(256) void k4_pin(const float* __restrict__ pin_w,
                                              const float* __restrict__ pin_b,
                                              float* __restrict__ ws) {
    __shared__ float sx[C][16];
    int tid = threadIdx.x;
    int bt = blockIdx.x >> 4;
    int n0 = (blockIdx.x & 15) << 4;
    const float* xn2 = ws + WS_XN2;
    float* po = ws + WS_PIN;
    for (int idx = tid; idx < 2048; idx += 256) {
        int ic = idx >> 4, nn = idx & 15;
        sx[ic][nn] = xn2[((size_t)bt * C + ic) * NSP + n0 + nn];
    }
    __syncthreads();
    for (int oc = tid; oc < HID2; oc += 256) {
        const float4* wr = (const float4*)(pin_w + (size_t)oc * C);
        float pb = pin_b[oc];
        float acc[16];
        #pragma unroll
        for (int nn = 0; nn < 16; ++nn) acc[nn] = pb;
        for (int ic4 = 0; ic4 < 32; ++ic4) {
            float4 w4 = wr[ic4];
            #pragma unroll
            for (int nn = 0; nn < 16; ++nn) {
                acc[nn] += w4.x * sx[ic4 * 4 + 0][nn] + w4.y * sx[ic4 * 4 + 1][nn]
                         + w4.z * sx[ic4 * 4 + 2][nn] + w4.w * sx[ic4 * 4 + 3][nn];
            }
        }
        float* ob = po + ((size_t)bt * HID2 + oc) * NSP + n0;
        #pragma unroll
        for (int nn = 0; nn < 16; ++nn) ob[nn] = acc[nn];
    }
}

// ---------------- K5: depthwise 3x3 + GLU (exact gelu) ----------------
__global__ __launch_bounds__(256) void k5_dwglu(const float* __restrict__ dw_w,
                                                const float* __restrict__ dw_b,
                                                float* __restrict__ ws) {
    __shared__ float sA[NSP], sG[NSP];
    int bt = blockIdx.x / HID;
    int c = blockIdx.x % HID;
    int px = threadIdx.x;
    int hh = px >> 4, wwp = px & 15;
    const float* po = ws + WS_PIN;
    sA[px] = po[((size_t)bt * HID2 + c) * NSP + px];
    sG[px] = po[((size_t)bt * HID2 + c + HID) * NSP + px];
    __syncthreads();
    float accA = dw_b[c], accG = dw_b[c + HID];
    #pragma unroll
    for (int kh = -1; kh <= 1; ++kh) {
        #pragma unroll
        for (int kw = -1; kw <= 1; ++kw) {
            int h2 = hh + kh, w2 = wwp + kw;
            bool ok = (h2 >= 0) & (h2 < 16) & (w2 >= 0) & (w2 < 16);
            float va = 0.f, vg = 0.f;
            if (ok) { int idx = h2 * 16 + w2; va = sA[idx]; vg = sG[idx]; }
            int kk = (kh + 1) * 3 + (kw + 1);
            accA += va * dw_w[(size_t)c * 9 + kk];
            accG += vg * dw_w[((size_t)c + HID) * 9 + kk];
        }
    }
    float gel = 0.5f * accA * (1.0f + erff(accA * 0.70710678118f));
    ws[WS_GLU + ((size_t)bt * HID + c) * NSP + px] = gel * accG;
}

// ---------------- K6: pout 1x1 conv + residual2 -> d_out x ----------------
__global__ __launch_bounds__(128) void k6_pout(const float* __restrict__ pout_w,
                                               const float* __restrict__ pout_b,
                                               const float* __restrict__ g2,
                                               float* __restrict__ ws, float* __restrict__ out) {
    __shared__ float sg[8][HID];
    int tid = threadIdx.x;
    int tb = blockIdx.x * 8;
    int bt = tb >> 8, n0 = tb & 255;
    const float* glu = ws + WS_GLU;
    for (int idx = tid; idx < 8 * HID; idx += 128) {
        int ic = idx >> 3, t = idx & 7;
        sg[t][ic] = glu[((size_t)bt * HID + ic) * NSP + n0 + t];
    }
    __syncthreads();
    int c = tid;
    const float4* wr4 = (const float4*)(pout_w + (size_t)c * HID);
    float acc[8];
    #pragma unroll
    for (int t = 0; t < 8; ++t) acc[t] = 0.f;
    for (int ic4 = 0; ic4 < 85; ++ic4) {
        float4 w4 = wr4[ic4];
        int ic = ic4 * 4;
        #pragma unroll
        for (int t = 0; t < 8; ++t) {
            acc[t] += w4.x * sg[t][ic] + w4.y * sg[t][ic + 1]
                    + w4.z * sg[t][ic + 2] + w4.w * sg[t][ic + 3];
        }
    }
    float pb = pout_b[c], gg = g2[c];
    const float* x1 = ws + WS_X1;
    for (int t = 0; t < 8; ++t) {
        size_t tok = tb + t;
        out[tok * C + c] = x1[tok * C + c] + gg * (acc[t] + pb);
    }
}

extern "C" void kernel_launch(void* const* d_in, const int* in_sizes, int n_in,
                              void* d_out, int out_size, void* d_ws, size_t ws_size,
                              hipStream_t stream) {
    const float* x      = (const float*)d_in[0];
    const float* bias   = (const float*)d_in[1];
    const float* ln1_s  = (const float*)d_in[2];
    const float* ln1_b  = (const float*)d_in[3];
    const float* qkv_w  = (const float*)d_in[4];
    const float* qkv_b  = (const float*)d_in[5];
    const float* proj_w = (const float*)d_in[6];
    const float* proj_b = (const float*)d_in[7];
    const float* bw1    = (const float*)d_in[8];
    const float* bb1    = (const float*)d_in[9];
    const float* bw2    = (const float*)d_in[10];
    const float* bb2    = (const float*)d_in[11];
    const float* ln2_s  = (const float*)d_in[12];
    const float* ln2_b  = (const float*)d_in[13];
    const float* pin_w  = (const float*)d_in[14];
    const float* pin_b  = (const float*)d_in[15];
    const float* dw_w   = (const float*)d_in[16];
    const float* dw_b   = (const float*)d_in[17];
    const float* pout_w = (const float*)d_in[18];
    const float* pout_b = (const float*)d_in[19];
    const float* gamma2 = (const float*)d_in[21];
    const float* gamma1 = (const float*)d_in[20];

    float* ws = (float*)d_ws;
    float* out = (float*)d_out;
    float* attn_out = out + (size_t)BB * NT * C;

    hipLaunchKernelGGL(k0_prep, dim3(1), dim3(64), 0, stream, bw1, bb1, bw2, ws + WS_MISC);
    hipLaunchKernelGGL(k1_ln_qkv, dim3(512), dim3(256), 0, stream, x, ln1_s, ln1_b, qkv_w, qkv_b, ws);
    hipLaunchKernelGGL(k2_attn, dim3(1024), dim3(256), 0, stream, bias, bb2, bw1, bb1, bw2, ws, attn_out);
    hipLaunchKernelGGL(k3_proj, dim3(4096), dim3(128), 0, stream, x, proj_w, proj_b, gamma1, ln2_s, ln2_b, ws);
    hipLaunchKernelGGL(k4_pin, dim3(256), dim3(256), 0, stream, pin_w, pin_b, ws);
    hipLaunchKernelGGL(k5_dwglu, dim3(16 * HID), dim3(256), 0, stream, dw_w, dw_b, ws);
    hipLaunchKernelGGL(k6_pout, dim3(512), dim3(128), 0, stream, pout_w, pout_b, gamma2, ws, out);
}

// Round 2
// 240.389 us; speedup vs baseline: 2.0511x; 2.0511x over previous
//
#include <hip/hip_runtime.h>
#include <hip/hip_bf16.h>
#include <math.h>

#define BB 4
#define NT 1024
#define NSP 256
#define C 128
#define HEADS 8
#define HID 340
#define HID2 680
#define EPS 1e-5f

// workspace float offsets
#define WS_Q    0
#define WS_K    524288
#define WS_VT   1048576
#define WS_AO   1572864
#define WS_X1   2097152
#define WS_XN2  2621440
#define WS_PIN  3145728
#define WS_GLU  5931008
#define WS_MISC 7323648

typedef __bf16 bf16x8 __attribute__((ext_vector_type(8)));
typedef float f32x4 __attribute__((ext_vector_type(4)));

// ---------------- K0: precompute piecewise-linear bias-MLP coefficients ----------------
__global__ void k0_prep(const float* __restrict__ bw1, const float* __restrict__ bb1,
                        const float* __restrict__ bw2, float* __restrict__ misc) {
    int t = threadIdx.x;
    if (t < HEADS) {
        float P = 0.f, Nn = 0.f;
        for (int k = 0; k < 16; ++k) {
            float w1 = bw1[k];
            float w2 = bw2[t * 16 + k];
            if (w1 > 0.f) P += w2 * w1; else Nn += w2 * w1;
        }
        misc[t] = P;
        misc[8 + t] = Nn;
    }
    if (t == 0) {
        int f = 1;
        for (int k = 0; k < 16; ++k) if (bb1[k] != 0.f) f = 0;
        misc[16] = (float)f;
    }
}

// ---------------- K1: LN1 + QKV projection (8 tokens / block) ----------------
__global__ __launch_bounds__(256) void k1_ln_qkv(
    const float* __restrict__ x, const float* __restrict__ s1, const float* __restrict__ b1,
    const float* __restrict__ qkv_w, const float* __restrict__ qkv_b, float* __restrict__ ws) {
    __shared__ float sxn[8][C];
    __shared__ float part[4][2];
    int tid = threadIdx.x;
    int g = tid >> 7, c = tid & 127;
    int wv = tid >> 6, lane = tid & 63;
    int tb = blockIdx.x * 8;

    for (int pass = 0; pass < 4; ++pass) {
        int tok = pass * 2 + g;
        float v = x[(size_t)(tb + tok) * C + c];
        float s = v, sq = v * v;
        #pragma unroll
        for (int off = 32; off; off >>= 1) { s += __shfl_xor(s, off); sq += __shfl_xor(sq, off); }
        if (lane == 0) { part[wv][0] = s; part[wv][1] = sq; }
        __syncthreads();
        float tot = part[g * 2][0] + part[g * 2 + 1][0];
        float tot2 = part[g * 2][1] + part[g * 2 + 1][1];
        float m = tot * (1.0f / C);
        float var = tot2 * (1.0f / C) - m * m;
        float inv = rsqrtf(var + EPS);
        sxn[tok][c] = (v - m) * inv * s1[c] + b1[c];
        __syncthreads();
    }

    float* qw = ws + WS_Q;
    float* kw = ws + WS_K;
    float* vtw = ws + WS_VT;
    for (int oo = tid; oo < 384; oo += 256) {
        const float4* wr = (const float4*)(qkv_w + (size_t)oo * C);
        float bbv = qkv_b[oo];
        float acc[8];
        #pragma unroll
        for (int t = 0; t < 8; ++t) acc[t] = bbv;
        #pragma unroll 4
        for (int ic4 = 0; ic4 < 32; ++ic4) {
            float4 w4 = wr[ic4];
            #pragma unroll
            for (int t = 0; t < 8; ++t) {
                acc[t] += w4.x * sxn[t][ic4 * 4 + 0] + w4.y * sxn[t][ic4 * 4 + 1]
                        + w4.z * sxn[t][ic4 * 4 + 2] + w4.w * sxn[t][ic4 * 4 + 3];
            }
        }
        int m3 = oo >> 7, h = (oo >> 4) & 7, dd = oo & 15;
        for (int t = 0; t < 8; ++t) {
            int tok = tb + t;
            int b = tok >> 10, i = tok & 1023;
            if (m3 == 0)      qw[(size_t)tok * C + h * 16 + dd] = acc[t] * 0.25f; // fold d^-0.5
            else if (m3 == 1) kw[(((size_t)b * 8 + h) * NT + i) * 16 + dd] = acc[t];
            else              vtw[(((size_t)b * 8 + h) * 16 + dd) * NT + i] = acc[t];
        }
    }
}

// ---------------- K2a: logits + bias-MLP + softmax + attn write (register-resident) ----------------
__global__ __launch_bounds__(256) void k2a_sm(
    const float* __restrict__ bias, const float* __restrict__ bb2v,
    const float* __restrict__ bw1v, const float* __restrict__ bb1v, const float* __restrict__ bw2v,
    const float* __restrict__ ws, float* __restrict__ attn_out) {
    __shared__ float sred[2][4][8];
    __shared__ float sPN[24];
    __shared__ float sw1[16], sb1[16], sw2[128];
    __shared__ int sfast;

    int tid = threadIdx.x;
    int blk = blockIdx.x;
    int b = blk >> 8;
    int i0 = (blk & 255) << 2;
    const float* qw = ws + WS_Q;
    const float* kw = ws + WS_K;
    const float* misc = ws + WS_MISC;

    // bias rows into registers (j = tid*4 .. tid*4+3)
    float bvr[4][4];
    #pragma unroll
    for (int r = 0; r < 4; ++r) {
        float4 t4 = *(const float4*)(bias + ((size_t)(b * NT + i0 + r)) * NT + tid * 4);
        bvr[r][0] = t4.x; bvr[r][1] = t4.y; bvr[r][2] = t4.z; bvr[r][3] = t4.w;
    }
    if (tid < 24) sPN[tid] = (tid < 16) ? misc[tid] : bb2v[tid - 16];
    if (tid >= 32 && tid < 48) { sw1[tid - 32] = bw1v[tid - 32]; sb1[tid - 32] = bb1v[tid - 32]; }
    if (tid >= 64 && tid < 192) sw2[tid - 64] = bw2v[tid - 64];
    if (tid == 0) sfast = (misc[16] != 0.0f) ? 1 : 0;
    __syncthreads();
    bool fast = (sfast != 0);
    int wv = tid >> 6, lane = tid & 63;

    for (int h = 0; h < HEADS; ++h) {
        // q rows are block-uniform -> force into SGPRs
        float qh[4][16];
        #pragma unroll
        for (int r = 0; r < 4; ++r) {
            const float* qb = qw + ((size_t)(b * NT + i0 + r)) * C + h * 16;
            #pragma unroll
            for (int dd = 0; dd < 16; ++dd)
                qh[r][dd] = __uint_as_float(__builtin_amdgcn_readfirstlane(__float_as_uint(qb[dd])));
        }
        float Ph = sPN[h], Nh = sPN[8 + h], c2 = sPN[16 + h];
        float vals[4][4];
        const float* kbase = kw + (size_t)(b * 8 + h) * NT * 16;
        #pragma unroll
        for (int jj = 0; jj < 4; ++jj) {
            const float4* kr = (const float4*)(kbase + (size_t)(tid * 4 + jj) * 16);
            float4 k0 = kr[0], k1 = kr[1], k2 = kr[2], k3 = kr[3];
            #pragma unroll
            for (int r = 0; r < 4; ++r) {
                float dot = qh[r][0] * k0.x + qh[r][1] * k0.y + qh[r][2] * k0.z + qh[r][3] * k0.w
                          + qh[r][4] * k1.x + qh[r][5] * k1.y + qh[r][6] * k1.z + qh[r][7] * k1.w
                          + qh[r][8] * k2.x + qh[r][9] * k2.y + qh[r][10] * k2.z + qh[r][11] * k2.w
                          + qh[r][12] * k3.x + qh[r][13] * k3.y + qh[r][14] * k3.z + qh[r][15] * k3.w;
                float bvv = bvr[r][jj];
                float lb;
                if (fast) {
                    lb = bvv * (bvv > 0.f ? Ph : Nh) + c2;
                } else {
                    lb = c2;
                    #pragma unroll
                    for (int k = 0; k < 16; ++k) {
                        float t = bvv * sw1[k] + sb1[k];
                        if (t > 0.f) lb += sw2[h * 16 + k] * t;
                    }
                }
                vals[r][jj] = dot + lb;
            }
        }
        // row max
        float mx[4];
        #pragma unroll
        for (int r = 0; r < 4; ++r)
            mx[r] = fmaxf(fmaxf(vals[r][0], vals[r][1]), fmaxf(vals[r][2], vals[r][3]));
        #pragma unroll
        for (int off = 32; off; off >>= 1) {
            #pragma unroll
            for (int r = 0; r < 4; ++r) mx[r] = fmaxf(mx[r], __shfl_xor(mx[r], off));
        }
        if (lane == 0) {
            #pragma unroll
            for (int r = 0; r < 4; ++r) sred[h & 1][r][wv] = mx[r];
        }
        __syncthreads();
        float sm[4];
        #pragma unroll
        for (int r = 0; r < 4; ++r) {
            float m = fmaxf(fmaxf(sred[h & 1][r][0], sred[h & 1][r][1]),
                            fmaxf(sred[h & 1][r][2], sred[h & 1][r][3]));
            float s = 0.f;
            #pragma unroll
            for (int jj = 0; jj < 4; ++jj) { vals[r][jj] = __expf(vals[r][jj] - m); s += vals[r][jj]; }
            sm[r] = s;
        }
        #pragma unroll
        for (int off = 32; off; off >>= 1) {
            #pragma unroll
            for (int r = 0; r < 4; ++r) sm[r] += __shfl_xor(sm[r], off);
        }
        if (lane == 0) {
            #pragma unroll
            for (int r = 0; r < 4; ++r) sred[h & 1][r][4 + wv] = sm[r];
        }
        __syncthreads();
        #pragma unroll
        for (int r = 0; r < 4; ++r) {
            float s = sred[h & 1][r][4] + sred[h & 1][r][5] + sred[h & 1][r][6] + sred[h & 1][r][7];
            float inv = 1.0f / s;
            float4 o;
            o.x = vals[r][0] * inv; o.y = vals[r][1] * inv;
            o.z = vals[r][2] * inv; o.w = vals[r][3] * inv;
            *(float4*)(attn_out + ((size_t)(b * 8 + h) * NT + i0 + r) * NT + tid * 4) = o;
        }
    }
}

// ---------------- K2b: PV via bf16 MFMA (A=attn rows, B=V^T staged in LDS) ----------------
__global__ __launch_bounds__(256) void k2b_pv(const float* __restrict__ attn,
                                              const float* __restrict__ ws_ro,
                                              float* __restrict__ ws_out) {
    __shared__ __bf16 sVT[16][1032];   // V^T bf16, padded row (2064 B -> 2-way banks, free)
    int tid = threadIdx.x;
    int blk = blockIdx.x;              // 512: bh = blk>>4, itile = blk&15
    int bh = blk >> 4;
    int i0 = (blk & 15) * 64;
    const float* vt = ws_ro + WS_VT + (size_t)bh * 16 * NT;

    // stage V_h^T as bf16 (64 KB fp32 -> 32 KB bf16)
    #pragma unroll
    for (int s = 0; s < 16; ++s) {
        int f4 = tid + 256 * s;        // 4096 float4s = 16 rows x 256
        int dd = f4 >> 8, jq = f4 & 255;
        float4 v4 = *(const float4*)(vt + ((size_t)dd << 10) + jq * 4);
        sVT[dd][jq * 4 + 0] = (__bf16)v4.x;
        sVT[dd][jq * 4 + 1] = (__bf16)v4.y;
        sVT[dd][jq * 4 + 2] = (__bf16)v4.z;
        sVT[dd][jq * 4 + 3] = (__bf16)v4.w;
    }
    __syncthreads();

    int wv = tid >> 6, lane = tid & 63;
    int row = lane & 15, kg = lane >> 4;   // A row / B col ; k-group
    const float* pbase = attn + ((size_t)bh * NT + i0 + wv * 16 + row) * NT;
    f32x4 acc = {0.f, 0.f, 0.f, 0.f};
    #pragma unroll 4
    for (int kt = 0; kt < 32; ++kt) {
        int k0 = kt * 32 + kg * 8;
        float4 a0 = *(const float4*)(pbase + k0);
        float4 a1 = *(const float4*)(pbase + k0 + 4);
        bf16x8 af;
        af[0] = (__bf16)a0.x; af[1] = (__bf16)a0.y; af[2] = (__bf16)a0.z; af[3] = (__bf16)a0.w;
        af[4] = (__bf16)a1.x; af[5] = (__bf16)a1.y; af[6] = (__bf16)a1.z; af[7] = (__bf16)a1.w;
        bf16x8 bfv = *(const bf16x8*)&sVT[row][k0];
        acc = __builtin_amdgcn_mfma_f32_16x16x32_bf16(af, bfv, acc, 0, 0, 0);
    }
    int b = bh >> 3, h = bh & 7;
    float* ao = ws_out + WS_AO;
    #pragma unroll
    for (int q = 0; q < 4; ++q) {
        int irow = i0 + wv * 16 + kg * 4 + q;    // C/D: row=(lane>>4)*4+q, col=lane&15
        ao[((size_t)(b * NT + irow)) * C + h * 16 + row] = acc[q];
    }
}

// ---------------- K3: proj + residual1 + LN2 ----------------
__global__ __launch_bounds__(128) void k3_proj(
    const float* __restrict__ x, const float* __restrict__ proj_w, const float* __restrict__ proj_b,
    const float* __restrict__ g1, const float* __restrict__ s2, const float* __restrict__ b2,
    float* __restrict__ ws) {
    __shared__ float sao[C];
    __shared__ float part[2][2];
    int tok = blockIdx.x;
    int c = threadIdx.x;
    const float* ao = ws + WS_AO;
    sao[c] = ao[(size_t)tok * C + c];
    __syncthreads();
    float acc = proj_b[c];
    const float4* wr = (const float4*)(proj_w + (size_t)c * C);
    const float4* ar = (const float4*)sao;
    #pragma unroll 8
    for (int q = 0; q < 32; ++q) {
        float4 w4 = wr[q], a4 = ar[q];
        acc += w4.x * a4.x + w4.y * a4.y + w4.z * a4.z + w4.w * a4.w;
    }
    float x1 = x[(size_t)tok * C + c] + g1[c] * acc;
    ws[WS_X1 + (size_t)tok * C + c] = x1;
    int wv = c >> 6, lane = c & 63;
    float s = x1, sq = x1 * x1;
    #pragma unroll
    for (int off = 32; off; off >>= 1) { s += __shfl_xor(s, off); sq += __shfl_xor(sq, off); }
    if (lane == 0) { part[wv][0] = s; part[wv][1] = sq; }
    __syncthreads();
    float tot = part[0][0] + part[1][0];
    float tot2 = part[0][1] + part[1][1];
    float m = tot * (1.0f / C);
    float var = tot2 * (1.0f / C) - m * m;
    float xn2 = (x1 - m) * rsqrtf(var + EPS) * s2[c] + b2[c];
    int bt = tok >> 8, n = tok & 255;
    ws[WS_XN2 + ((size_t)bt * C + c) * NSP + n] = xn2;
}

// ---------------- K4: pin 1x1 conv (GEMM, 8 spatial / block) ----------------
__global__ __launch_bounds__(256) void k4_pin(const float* __restrict__ pin_w,
                                              const float* __restrict__ pin_b,
                                              float* __restrict__ ws) {
    __shared__ float sx[C][8];
    int tid = threadIdx.x;
    int bt = blockIdx.x >> 5;
    int n0 = (blockIdx.x & 31) << 3;
    const float* xn2 = ws + WS_XN2;
    float* po = ws + WS_PIN;
    for (int idx = tid; idx < 1024; idx += 256) {
        int ic = idx >> 3, nn = idx & 7;
        sx[ic][nn] = xn2[((size_t)bt * C + ic) * NSP + n0 + nn];
    }
    __syncthreads();
    for (int oc = tid; oc < HID2; oc += 256) {
        const float4* wr = (const float4*)(pin_w + (size_t)oc * C);
        float pb = pin_b[oc];
        float acc[8];
        #pragma unroll
        for (int nn = 0; nn < 8; ++nn) acc[nn] = pb;
        for (int ic4 = 0; ic4 < 32; ++ic4) {
            float4 w4 = wr[ic4];
            #pragma unroll
            for (int nn = 0; nn < 8; ++nn) {
                acc[nn] += w4.x * sx[ic4 * 4 + 0][nn] + w4.y * sx[ic4 * 4 + 1][nn]
                         + w4.z * sx[ic4 * 4 + 2][nn] + w4.w * sx[ic4 * 4 + 3][nn];
            }
        }
        float* ob = po + ((size_t)bt * HID2 + oc) * NSP + n0;
        #pragma unroll
        for (int nn = 0; nn < 8; ++nn) ob[nn] = acc[nn];
    }
}

// ---------------- K5: depthwise 3x3 + GLU (exact gelu) ----------------
__global__ __launch_bounds__(256) void k5_dwglu(const float* __restrict__ dw_w,
                                                const float* __restrict__ dw_b,
                                                float* __restrict__ ws) {
    __shared__ float sA[NSP], sG[NSP];
    int bt = blockIdx.x / HID;
    int c = blockIdx.x % HID;
    int px = threadIdx.x;
    int hh = px >> 4, wwp = px & 15;
    const float* po = ws + WS_PIN;
    sA[px] = po[((size_t)bt * HID2 + c) * NSP + px];
    sG[px] = po[((size_t)bt * HID2 + c + HID) * NSP + px];
    __syncthreads();
    float accA = dw_b[c], accG = dw_b[c + HID];
    #pragma unroll
    for (int kh = -1; kh <= 1; ++kh) {
        #pragma unroll
        for (int kw = -1; kw <= 1; ++kw) {
            int h2 = hh + kh, w2 = wwp + kw;
            bool ok = (h2 >= 0) & (h2 < 16) & (w2 >= 0) & (w2 < 16);
            float va = 0.f, vg = 0.f;
            if (ok) { int idx = h2 * 16 + w2; va = sA[idx]; vg = sG[idx]; }
            int kk = (kh + 1) * 3 + (kw + 1);
            accA += va * dw_w[(size_t)c * 9 + kk];
            accG += vg * dw_w[((size_t)c + HID) * 9 + kk];
        }
    }
    float gel = 0.5f * accA * (1.0f + erff(accA * 0.70710678118f));
    ws[WS_GLU + ((size_t)bt * HID + c) * NSP + px] = gel * accG;
}

// ---------------- K6: pout 1x1 conv + residual2 -> d_out x ----------------
__global__ __launch_bounds__(128) void k6_pout(const float* __restrict__ pout_w,
                                               const float* __restrict__ pout_b,
                                               const float* __restrict__ g2,
                                               float* __restrict__ ws, float* __restrict__ out) {
    __shared__ float sg[8][HID];
    int tid = threadIdx.x;
    int tb = blockIdx.x * 8;
    int bt = tb >> 8, n0 = tb & 255;
    const float* glu = ws + WS_GLU;
    for (int idx = tid; idx < 8 * HID; idx += 128) {
        int ic = idx >> 3, t = idx & 7;
        sg[t][ic] = glu[((size_t)bt * HID + ic) * NSP + n0 + t];
    }
    __syncthreads();
    int c = tid;
    const float4* wr4 = (const float4*)(pout_w + (size_t)c * HID);
    float acc[8];
    #pragma unroll
    for (int t = 0; t < 8; ++t) acc[t] = 0.f;
    for (int ic4 = 0; ic4 < 85; ++ic4) {
        float4 w4 = wr4[ic4];
        int ic = ic4 * 4;
        #pragma unroll
        for (int t = 0; t < 8; ++t) {
            acc[t] += w4.x * sg[t][ic] + w4.y * sg[t][ic + 1]
                    + w4.z * sg[t][ic + 2] + w4.w * sg[t][ic + 3];
        }
    }
    float pb = pout_b[c], gg = g2[c];
    const float* x1 = ws + WS_X1;
    for (int t = 0; t < 8; ++t) {
        size_t tok = tb + t;
        out[tok * C + c] = x1[tok * C + c] + gg * (acc[t] + pb);
    }
}

extern "C" void kernel_launch(void* const* d_in, const int* in_sizes, int n_in,
                              void* d_out, int out_size, void* d_ws, size_t ws_size,
                              hipStream_t stream) {
    const float* x      = (const float*)d_in[0];
    const float* bias   = (const float*)d_in[1];
    const float* ln1_s  = (const float*)d_in[2];
    const float* ln1_b  = (const float*)d_in[3];
    const float* qkv_w  = (const float*)d_in[4];
    const float* qkv_b  = (const float*)d_in[5];
    const float* proj_w = (const float*)d_in[6];
    const float* proj_b = (const float*)d_in[7];
    const float* bw1    = (const float*)d_in[8];
    const float* bb1    = (const float*)d_in[9];
    const float* bw2    = (const float*)d_in[10];
    const float* bb2    = (const float*)d_in[11];
    const float* ln2_s  = (const float*)d_in[12];
    const float* ln2_b  = (const float*)d_in[13];
    const float* pin_w  = (const float*)d_in[14];
    const float* pin_b  = (const float*)d_in[15];
    const float* dw_w   = (const float*)d_in[16];
    const float* dw_b   = (const float*)d_in[17];
    const float* pout_w = (const float*)d_in[18];
    const float* pout_b = (const float*)d_in[19];
    const float* gamma1 = (const float*)d_in[20];
    const float* gamma2 = (const float*)d_in[21];

    float* ws = (float*)d_ws;
    float* out = (float*)d_out;
    float* attn_out = out + (size_t)BB * NT * C;

    hipLaunchKernelGGL(k0_prep, dim3(1), dim3(64), 0, stream, bw1, bb1, bw2, ws + WS_MISC);
    hipLaunchKernelGGL(k1_ln_qkv, dim3(512), dim3(256), 0, stream, x, ln1_s, ln1_b, qkv_w, qkv_b, ws);
    hipLaunchKernelGGL(k2a_sm, dim3(1024), dim3(256), 0, stream, bias, bb2, bw1, bb1, bw2, ws, attn_out);
    hipLaunchKernelGGL(k2b_pv, dim3(512), dim3(256), 0, stream, attn_out, ws, ws);
    hipLaunchKernelGGL(k3_proj, dim3(4096), dim3(128), 0, stream, x, proj_w, proj_b, gamma1, ln2_s, ln2_b, ws);
    hipLaunchKernelGGL(k4_pin, dim3(512), dim3(256), 0, stream, pin_w, pin_b, ws);
    hipLaunchKernelGGL(k5_dwglu, dim3(16 * HID), dim3(256), 0, stream, dw_w, dw_b, ws);
    hipLaunchKernelGGL(k6_pout, dim3(512), dim3(128), 0, stream, pout_w, pout_b, gamma2, ws, out);
}